// Round 6
// baseline (173.846 us; speedup 1.0000x reference)
//
#include <hip/hip_runtime.h>
#include <hip/hip_bf16.h>
#include <math.h>

#define NPTS   65536
#define NS     16
#define WID    128
#define NHID   3
#define CAP    24576
#define CZ     -25.33f          // ln(1e-11): drop (point,s) when min window logit below this
#define CSTR   32               // counts stride in ints (128 B -> one cache line per counter)

// ws layout:
//   [0, 2KB)                   counts[16] padded 128B apart
//   [OFF_IDX, +1.50MB)         idx buckets
//   [OFF_WF,  +1.50MB)         f16 hidden-weight MFMA fragments
//   [OFF_WO,  +64KB)           f16 output-weight row-0 MFMA fragments
#define OFF_IDX 2048
#define OFF_WF  (OFF_IDX + NS * CAP * 4)
#define OFF_WO  (OFF_WF + NS * NHID * WID * WID * 2)

typedef _Float16 f16x8 __attribute__((ext_vector_type(8)));
typedef _Float16 f16x4 __attribute__((ext_vector_type(4)));
typedef float    f32x4 __attribute__((ext_vector_type(4)));

// tanh(x) = 1 - 2/(exp2(x*2*log2e)+1); exp2 saturates cleanly so no clamp needed
__device__ __forceinline__ float tanh5(float x) {
    float e = __builtin_amdgcn_exp2f(x * 2.8853900817779268f);
    float r = __builtin_amdgcn_rcpf(e + 1.f);
    return fmaf(-2.f, r, 1.f);
}
__device__ __forceinline__ float sigmf(float z) {
    float e = __builtin_amdgcn_exp2f(-z * 1.4426950408889634f);
    return __builtin_amdgcn_rcpf(1.f + e);
}

// prepack WF (hidden) + WoutF (output row-0 frags) + zero padded counts
__global__ void init_kernel(int* __restrict__ counts,
                            const float* __restrict__ Wh, _Float16* __restrict__ WF,
                            const float* __restrict__ Wout, _Float16* __restrict__ WoutF) {
    int b = blockIdx.x, t = threadIdx.x;
    if (b == 0 && t < NS) counts[t * CSTR] = 0;
    if (b < 384) {
        // WF frag idx = ((sl*8 + vt)*4 + kk)*64 + lane holds
        // Wh[sl][v = vt*16 + (lane&15)][w = kk*32 + (lane>>4)*8 .. +7]
        int g = b * 256 + t;
        int sl = g >> 11, r = g & 2047;
        int vt = r >> 8, kk = (r >> 6) & 3, lane = r & 63;
        int v = vt * 16 + (lane & 15);
        int w0 = kk * 32 + (lane >> 4) * 8;
        const float* src = Wh + (sl << 14) + v * WID + w0;
        float4 a = *(const float4*)src;
        float4 c = *(const float4*)(src + 4);
        f16x8 o;
        o[0] = (_Float16)a.x; o[1] = (_Float16)a.y; o[2] = (_Float16)a.z; o[3] = (_Float16)a.w;
        o[4] = (_Float16)c.x; o[5] = (_Float16)c.y; o[6] = (_Float16)c.z; o[7] = (_Float16)c.w;
        ((f16x8*)WF)[g] = o;
    } else {
        // WoutF frag idx = (s*4 + kk)*64 + lane: only A-row 0 nonzero = Wout[s][k]
        int g = (b - 384) * 256 + t;          // 4096 frags
        int s = g >> 8, kk = (g >> 6) & 3, lane = g & 63;
        f16x8 o = (f16x8)(_Float16)0.f;
        if ((lane & 15) == 0) {
            int w0 = kk * 32 + (lane >> 4) * 8;
            const float* src = Wout + s * WID + w0;
            float4 a = *(const float4*)src;
            float4 c = *(const float4*)(src + 4);
            o[0] = (_Float16)a.x; o[1] = (_Float16)a.y; o[2] = (_Float16)a.z; o[3] = (_Float16)a.w;
            o[4] = (_Float16)c.x; o[5] = (_Float16)c.y; o[6] = (_Float16)c.z; o[7] = (_Float16)c.w;
        }
        ((f16x8*)WoutF)[g] = o;
    }
}

// hierarchical compaction: wave ballot -> LDS wave counts -> 1 global atomic per (block,s)
__global__ void bucket_kernel(const float* __restrict__ x,
                              const float* __restrict__ mu_min, const float* __restrict__ sd_min,
                              const float* __restrict__ mu_max, const float* __restrict__ sd_max,
                              int* counts, int* __restrict__ idx,
                              float* __restrict__ out) {
    __shared__ int wcnt[NS][4];
    __shared__ int wbase[NS][4];
    __shared__ int bbase[NS];
    int t = threadIdx.x, lane = t & 63, wid = t >> 6;
    int n = blockIdx.x * 256 + t;
    float xv = x[n];
    out[n] = 0.f;                       // fused out-zero (runs before any mlp launch)
    unsigned long long ltmask = (1ULL << lane) - 1ULL;
    unsigned mbits = 0;
    #pragma unroll
    for (int s = 0; s < NS; ++s) {
        float z1 = __fdividef(xv - mu_min[s], sd_min[s]);
        float z2 = __fdividef(mu_max[s] - xv, sd_max[s]);
        bool m = (z1 > CZ) && (z2 > CZ);
        mbits |= (unsigned)m << s;
        unsigned long long mk = __ballot(m);
        if (lane == 0) wcnt[s][wid] = __popcll(mk);
    }
    __syncthreads();
    if (t < NS) {
        int c0 = wcnt[t][0], c1 = wcnt[t][1], c2 = wcnt[t][2], c3 = wcnt[t][3];
        wbase[t][0] = 0; wbase[t][1] = c0; wbase[t][2] = c0 + c1; wbase[t][3] = c0 + c1 + c2;
        bbase[t] = atomicAdd(&counts[t * CSTR], c0 + c1 + c2 + c3);
    }
    __syncthreads();
    #pragma unroll
    for (int s = 0; s < NS; ++s) {
        bool m = (mbits >> s) & 1;
        unsigned long long mk = __ballot(m);
        if (m) {
            int pos = __popcll(mk & ltmask);
            int g = bbase[s] + wbase[s][wid] + pos;
            if (g < CAP) idx[s * CAP + g] = n;
        }
    }
}

// Wave-autonomous MLP: each wave owns 16 points; h lives in B-fragments in
// registers; per-layer D->B redistribution via wave-private 4KB LDS scratch
// (XOR-swizzled 256B rows); NO __syncthreads anywhere.
__global__ __launch_bounds__(256, 5) void mlp_kernel(
        const float* __restrict__ x,
        const float* __restrict__ W0,   const float* __restrict__ b0,
        const _Float16* __restrict__ WF, const float* __restrict__ bh,
        const _Float16* __restrict__ WoutF, const float* __restrict__ bout,
        const float* __restrict__ centres, const float* __restrict__ scales,
        const float* __restrict__ mu_min,  const float* __restrict__ sd_min,
        const float* __restrict__ mu_max,  const float* __restrict__ sd_max,
        const int* __restrict__ counts, const int* __restrict__ idx,
        float* __restrict__ out) {
    __shared__ __align__(16) char scr[4][4096];   // per-wave private scratch

    int s = blockIdx.x;
    int cnt = counts[s * CSTR]; if (cnt > CAP) cnt = CAP;
    int t = threadIdx.x, lane = t & 63, w = t >> 6;
    int base = blockIdx.y * 64 + w * 16;          // this wave's 16-point base
    if (base >= cnt) return;                       // wave-uniform exit, no barriers exist
    int g = lane >> 4, p = lane & 15;
    int swz = (p & 7) << 4;                        // m214 row-swizzle for 256B rows
    char* S = scr[w];

    // ---- prologue: per-point window/input (lanes duplicate across g) ----
    int slot = base + p;
    bool live = slot < cnt;
    int n = 0; float xi = 0.f, wmv = 0.f;
    if (live) {
        n = idx[s * CAP + slot];
        float xv = x[n];
        float wl = sigmf(__fdividef(xv - mu_min[s], sd_min[s]));
        float wh = sigmf(__fdividef(mu_max[s] - xv, sd_max[s]));
        wmv = wl * wh;
        xi = __fdividef(xv - centres[s], fmaxf(scales[s], 1e-8f));
    }

    // ---- layer 0: compute B-fragments directly (no LDS) ----
    // B-frag kk, elem j: h0[v = kk*32 + g*8 + j][point p]
    f16x8 B[4];
    const float* W0p = W0 + s * WID;
    const float* b0p = b0 + s * WID;
    #pragma unroll
    for (int kk = 0; kk < 4; ++kk) {
        int v0 = kk * 32 + g * 8;
        float4 wa = *(const float4*)(W0p + v0), wb = *(const float4*)(W0p + v0 + 4);
        float4 ba = *(const float4*)(b0p + v0), bb = *(const float4*)(b0p + v0 + 4);
        f16x8 hv;
        hv[0] = (_Float16)tanh5(fmaf(wa.x, xi, ba.x));
        hv[1] = (_Float16)tanh5(fmaf(wa.y, xi, ba.y));
        hv[2] = (_Float16)tanh5(fmaf(wa.z, xi, ba.z));
        hv[3] = (_Float16)tanh5(fmaf(wa.w, xi, ba.w));
        hv[4] = (_Float16)tanh5(fmaf(wb.x, xi, bb.x));
        hv[5] = (_Float16)tanh5(fmaf(wb.y, xi, bb.y));
        hv[6] = (_Float16)tanh5(fmaf(wb.z, xi, bb.z));
        hv[7] = (_Float16)tanh5(fmaf(wb.w, xi, bb.w));
        B[kk] = hv;
    }

    // ---- hidden layers: 8 acc tiles x 4 chained MFMAs; D->tanh->scratch->B ----
    for (int l = 0; l < NHID; ++l) {
        const f16x8* WFp = (const f16x8*)WF + (size_t)(s * NHID + l) * 2048;
        const float* bhp = bh + (s * NHID + l) * WID;
        f32x4 acc[8];
        #pragma unroll
        for (int vt = 0; vt < 8; ++vt) {
            f32x4 a = *(const f32x4*)(bhp + vt * 16 + g * 4);   // bias fold (D row = vt*16+4g+reg)
            #pragma unroll
            for (int kk = 0; kk < 4; ++kk) {
                f16x8 af = WFp[(vt * 4 + kk) * 64 + lane];
                a = __builtin_amdgcn_mfma_f32_16x16x32_f16(af, B[kk], a, 0, 0, 0);
            }
            acc[vt] = a;
        }
        // epilogue: tanh + f16 + wave-private scratch write (row p, v0 = 4g+16vt)
        #pragma unroll
        for (int vt = 0; vt < 8; ++vt) {
            f16x4 q;
            q[0] = (_Float16)tanh5(acc[vt][0]);
            q[1] = (_Float16)tanh5(acc[vt][1]);
            q[2] = (_Float16)tanh5(acc[vt][2]);
            q[3] = (_Float16)tanh5(acc[vt][3]);
            *(f16x4*)(S + p * 256 + ((((g * 4 + vt * 16) * 2)) ^ swz)) = q;
        }
        // re-gather as B-frags (row p, v0 = kk*32 + g*8); in-wave lgkmcnt orders W->R
        #pragma unroll
        for (int kk = 0; kk < 4; ++kk)
            B[kk] = *(const f16x8*)(S + p * 256 + ((((kk * 32 + g * 8) * 2)) ^ swz));
    }

    // ---- output layer: row-0 A-frag MFMAs; D row0 = raw[p] at lanes 0..15 ----
    {
        float bo = bout[s];
        f32x4 oacc = (f32x4){bo, bo, bo, bo};
        const f16x8* WOp = (const f16x8*)WoutF + s * 256;
        #pragma unroll
        for (int kk = 0; kk < 4; ++kk)
            oacc = __builtin_amdgcn_mfma_f32_16x16x32_f16(WOp[kk * 64 + lane], B[kk], oacc, 0, 0, 0);
        if (g == 0 && live) atomicAdd(&out[n], wmv * oacc[0]);
    }
}

extern "C" void kernel_launch(void* const* d_in, const int* in_sizes, int n_in,
                              void* d_out, int out_size, void* d_ws, size_t ws_size,
                              hipStream_t stream) {
    const float* x       = (const float*)d_in[0];
    const float* W0      = (const float*)d_in[1];
    const float* b0      = (const float*)d_in[2];
    const float* Wh      = (const float*)d_in[3];
    const float* bh      = (const float*)d_in[4];
    const float* Wout    = (const float*)d_in[5];
    const float* bout    = (const float*)d_in[6];
    const float* centres = (const float*)d_in[7];
    const float* scales  = (const float*)d_in[8];
    const float* mu_min  = (const float*)d_in[9];
    const float* sd_min  = (const float*)d_in[10];
    const float* mu_max  = (const float*)d_in[11];
    const float* sd_max  = (const float*)d_in[12];
    float* out = (float*)d_out;
    char* ws = (char*)d_ws;
    int*      counts = (int*)ws;
    int*      idx    = (int*)(ws + OFF_IDX);
    _Float16* WF     = (_Float16*)(ws + OFF_WF);
    _Float16* WoutF  = (_Float16*)(ws + OFF_WO);

    init_kernel<<<dim3(400), dim3(256), 0, stream>>>(counts, Wh, WF, Wout, WoutF);
    bucket_kernel<<<dim3(NPTS / 256), dim3(256), 0, stream>>>(x, mu_min, sd_min, mu_max, sd_max,
                                                              counts, idx, out);
    dim3 grid(NS, CAP / 64);
    mlp_kernel<<<grid, dim3(256), 0, stream>>>(x, W0, b0, WF, bh, WoutF, bout,
                                               centres, scales, mu_min, sd_min, mu_max, sd_max,
                                               counts, idx, out);
}

// Round 7
// 162.519 us; speedup vs baseline: 1.0697x; 1.0697x over previous
//
#include <hip/hip_runtime.h>
#include <hip/hip_bf16.h>
#include <math.h>

#define NPTS   65536
#define NS     16
#define WID    128
#define NHID   3
#define CAP    24576
#define CZ     -25.33f          // ln(1e-11): drop (point,s) when min window logit below this
#define CSTR   32               // counts stride in ints (128 B -> one cache line per counter)

// ws layout:
//   [0, 2KB)                   counts[16] padded 128B apart (memset to 0 host-side)
//   [OFF_IDX, +1.50MB)         idx buckets
//   [OFF_WF,  +1.50MB)         f16 hidden-weight MFMA fragments
//   [OFF_WO,  +64KB)           f16 output-weight row-0 MFMA fragments
#define OFF_IDX 2048
#define OFF_WF  (OFF_IDX + NS * CAP * 4)
#define OFF_WO  (OFF_WF + NS * NHID * WID * WID * 2)

typedef _Float16 f16x8 __attribute__((ext_vector_type(8)));
typedef _Float16 f16x4 __attribute__((ext_vector_type(4)));
typedef float    f32x4 __attribute__((ext_vector_type(4)));

// tanh(x) = 1 - 2/(exp2(x*2*log2e)+1); exp2 saturates cleanly so no clamp needed
__device__ __forceinline__ float tanh5(float x) {
    float e = __builtin_amdgcn_exp2f(x * 2.8853900817779268f);
    float r = __builtin_amdgcn_rcpf(e + 1.f);
    return fmaf(-2.f, r, 1.f);
}
__device__ __forceinline__ float sigmf(float z) {
    float e = __builtin_amdgcn_exp2f(-z * 1.4426950408889634f);
    return __builtin_amdgcn_rcpf(1.f + e);
}

// Fused prep: blocks 0..255 bucket+out-zero; 256..639 WF pack; 640..655 WoutF pack.
// counts must be pre-zeroed (hipMemsetAsync in kernel_launch).
__global__ void prep_kernel(const float* __restrict__ x,
                            const float* __restrict__ mu_min, const float* __restrict__ sd_min,
                            const float* __restrict__ mu_max, const float* __restrict__ sd_max,
                            int* counts, int* __restrict__ idx, float* __restrict__ out,
                            const float* __restrict__ Wh, _Float16* __restrict__ WF,
                            const float* __restrict__ Wout, _Float16* __restrict__ WoutF) {
    __shared__ int wcnt[NS][4];
    __shared__ int wbase[NS][4];
    __shared__ int bbase[NS];
    int b = blockIdx.x, t = threadIdx.x;
    if (b < 256) {
        int lane = t & 63, wid = t >> 6;
        int n = b * 256 + t;
        float xv = x[n];
        out[n] = 0.f;                       // fused out-zero (before any mlp launch)
        unsigned long long ltmask = (1ULL << lane) - 1ULL;
        unsigned mbits = 0;
        #pragma unroll
        for (int s = 0; s < NS; ++s) {
            float z1 = __fdividef(xv - mu_min[s], sd_min[s]);
            float z2 = __fdividef(mu_max[s] - xv, sd_max[s]);
            bool m = (z1 > CZ) && (z2 > CZ);
            mbits |= (unsigned)m << s;
            unsigned long long mk = __ballot(m);
            if (lane == 0) wcnt[s][wid] = __popcll(mk);
        }
        __syncthreads();
        if (t < NS) {
            int c0 = wcnt[t][0], c1 = wcnt[t][1], c2 = wcnt[t][2], c3 = wcnt[t][3];
            wbase[t][0] = 0; wbase[t][1] = c0; wbase[t][2] = c0 + c1; wbase[t][3] = c0 + c1 + c2;
            bbase[t] = atomicAdd(&counts[t * CSTR], c0 + c1 + c2 + c3);
        }
        __syncthreads();
        #pragma unroll
        for (int s = 0; s < NS; ++s) {
            bool m = (mbits >> s) & 1;
            unsigned long long mk = __ballot(m);
            if (m) {
                int pos = __popcll(mk & ltmask);
                int g = bbase[s] + wbase[s][wid] + pos;
                if (g < CAP) idx[s * CAP + g] = n;
            }
        }
    } else if (b < 640) {
        // WF frag idx = ((sl*8 + vt)*4 + kk)*64 + lane holds
        // Wh[sl][v = vt*16 + (lane&15)][w = kk*32 + (lane>>4)*8 .. +7]
        int g = (b - 256) * 256 + t;
        int sl = g >> 11, r = g & 2047;
        int vt = r >> 8, kk = (r >> 6) & 3, lane = r & 63;
        int v = vt * 16 + (lane & 15);
        int w0 = kk * 32 + (lane >> 4) * 8;
        const float* src = Wh + (sl << 14) + v * WID + w0;
        float4 a = *(const float4*)src;
        float4 c = *(const float4*)(src + 4);
        f16x8 o;
        o[0] = (_Float16)a.x; o[1] = (_Float16)a.y; o[2] = (_Float16)a.z; o[3] = (_Float16)a.w;
        o[4] = (_Float16)c.x; o[5] = (_Float16)c.y; o[6] = (_Float16)c.z; o[7] = (_Float16)c.w;
        ((f16x8*)WF)[g] = o;
    } else {
        // WoutF frag idx = (s*4 + kk)*64 + lane: only A-row 0 nonzero = Wout[s][k]
        int g = (b - 640) * 256 + t;          // 4096 frags
        int s = g >> 8, kk = (g >> 6) & 3, lane = g & 63;
        f16x8 o = (f16x8)(_Float16)0.f;
        if ((lane & 15) == 0) {
            int w0 = kk * 32 + (lane >> 4) * 8;
            const float* src = Wout + s * WID + w0;
            float4 a = *(const float4*)src;
            float4 c = *(const float4*)(src + 4);
            o[0] = (_Float16)a.x; o[1] = (_Float16)a.y; o[2] = (_Float16)a.z; o[3] = (_Float16)a.w;
            o[4] = (_Float16)c.x; o[5] = (_Float16)c.y; o[6] = (_Float16)c.z; o[7] = (_Float16)c.w;
        }
        ((f16x8*)WoutF)[g] = o;
    }
}

// One hidden layer, wave-autonomous: 8 vt sub-tiles; rolling 2-slice scratch;
// B_next[kk] assembled after vt=2kk+1 (lane-group g needs vt = 2kk + (g>>1)).
__device__ __forceinline__ void layer_body(const f16x8* __restrict__ WFp,
                                           const float* __restrict__ bhp,
                                           char* Sw, int lane, int g,
                                           const int (&wof)[4], const int (&rof)[4],
                                           const f16x8 (&Bin)[4][4], f16x8 (&Bout)[4][4]) {
    #pragma unroll
    for (int vt = 0; vt < 8; ++vt) {
        f32x4 bias = *(const f32x4*)(bhp + vt * 16 + g * 4);   // D row = vt*16+4g+reg
        f16x8 af[4];
        #pragma unroll
        for (int kk = 0; kk < 4; ++kk) af[kk] = WFp[(vt * 4 + kk) * 64 + lane];
        f32x4 acc[4];
        #pragma unroll
        for (int pg = 0; pg < 4; ++pg) acc[pg] = bias;
        #pragma unroll
        for (int kk = 0; kk < 4; ++kk)
            #pragma unroll
            for (int pg = 0; pg < 4; ++pg)
                acc[pg] = __builtin_amdgcn_mfma_f32_16x16x32_f16(af[kk], Bin[pg][kk], acc[pg], 0, 0, 0);
        #pragma unroll
        for (int pg = 0; pg < 4; ++pg) {
            f16x4 q;
            q[0] = (_Float16)tanh5(acc[pg][0]);
            q[1] = (_Float16)tanh5(acc[pg][1]);
            q[2] = (_Float16)tanh5(acc[pg][2]);
            q[3] = (_Float16)tanh5(acc[pg][3]);
            *(f16x4*)(Sw + ((vt & 1) << 11) + wof[pg]) = q;
        }
        if (vt & 1) {
            const int kk = vt >> 1;
            #pragma unroll
            for (int pg = 0; pg < 4; ++pg)
                Bout[pg][kk] = *(const f16x8*)(Sw + rof[pg]);
        }
    }
}

// Wave-autonomous MLP: each wave owns 64 points (4 pgroups); h in B-fragments in
// registers; rolling 4KB/wave scratch; NO __syncthreads anywhere.
__global__ __launch_bounds__(256, 2) void mlp_kernel(
        const float* __restrict__ x,
        const float* __restrict__ W0,   const float* __restrict__ b0,
        const _Float16* __restrict__ WF, const float* __restrict__ bh,
        const _Float16* __restrict__ WoutF, const float* __restrict__ bout,
        const float* __restrict__ centres, const float* __restrict__ scales,
        const float* __restrict__ mu_min,  const float* __restrict__ sd_min,
        const float* __restrict__ mu_max,  const float* __restrict__ sd_max,
        const int* __restrict__ counts, const int* __restrict__ idx,
        float* __restrict__ out) {
    __shared__ __align__(16) char scr[4][4096];   // per-wave rolling 2-slice scratch

    int s = blockIdx.y;
    int cnt = counts[s * CSTR]; if (cnt > CAP) cnt = CAP;
    int t = threadIdx.x, lane = t & 63, w = t >> 6;
    int wslot0 = blockIdx.x * 256 + w * 64;       // this wave's 64-point base
    if (wslot0 >= cnt) return;                    // wave-uniform exit; no barriers exist
    int g = lane >> 4, p = lane & 15;
    char* Sw = scr[w];

    int wof[4], rof[4];
    #pragma unroll
    for (int pg = 0; pg < 4; ++pg) {
        int pt = pg * 16 + p;
        int sw = ((pt >> 2) & 1) << 4;
        wof[pg] = pt * 32 + ((g * 8) ^ sw);
        rof[pg] = ((g >> 1) << 11) + pt * 32 + (((g & 1) * 16) ^ sw);
    }

    // ---- prologue: per-pgroup point data (dup across g; wmv=0 marks dead) ----
    int   n[4]; float wmv[4], xi[4];
    #pragma unroll
    for (int pg = 0; pg < 4; ++pg) {
        int slot = wslot0 + pg * 16 + p;
        float xiv = 0.f, wv = 0.f; int nn = 0;
        if (slot < cnt) {
            nn = idx[s * CAP + slot];
            float xv = x[nn];
            float wl = sigmf(__fdividef(xv - mu_min[s], sd_min[s]));
            float wh = sigmf(__fdividef(mu_max[s] - xv, sd_max[s]));
            wv = wl * wh;
            xiv = __fdividef(xv - centres[s], fmaxf(scales[s], 1e-8f));
        }
        n[pg] = nn; wmv[pg] = wv; xi[pg] = xiv;
    }

    // ---- layer 0: build B-fragments directly; weights loaded once per kk ----
    f16x8 Ba[4][4], Bb[4][4];
    {
        const float* W0p = W0 + s * WID;
        const float* b0p = b0 + s * WID;
        #pragma unroll
        for (int kk = 0; kk < 4; ++kk) {
            int v0 = kk * 32 + g * 8;
            float4 wa = *(const float4*)(W0p + v0), wb = *(const float4*)(W0p + v0 + 4);
            float4 ba = *(const float4*)(b0p + v0), bb = *(const float4*)(b0p + v0 + 4);
            #pragma unroll
            for (int pg = 0; pg < 4; ++pg) {
                float xiv = xi[pg];
                f16x8 hv;
                hv[0] = (_Float16)tanh5(fmaf(wa.x, xiv, ba.x));
                hv[1] = (_Float16)tanh5(fmaf(wa.y, xiv, ba.y));
                hv[2] = (_Float16)tanh5(fmaf(wa.z, xiv, ba.z));
                hv[3] = (_Float16)tanh5(fmaf(wa.w, xiv, ba.w));
                hv[4] = (_Float16)tanh5(fmaf(wb.x, xiv, bb.x));
                hv[5] = (_Float16)tanh5(fmaf(wb.y, xiv, bb.y));
                hv[6] = (_Float16)tanh5(fmaf(wb.z, xiv, bb.z));
                hv[7] = (_Float16)tanh5(fmaf(wb.w, xiv, bb.w));
                Ba[pg][kk] = hv;
            }
        }
    }

    // ---- 3 hidden layers, alternating fragment buffers ----
    const f16x8* WF8 = (const f16x8*)WF;
    const float* bh0 = bh + s * NHID * WID;
    layer_body(WF8 + (size_t)(s * NHID + 0) * 2048, bh0,           Sw, lane, g, wof, rof, Ba, Bb);
    layer_body(WF8 + (size_t)(s * NHID + 1) * 2048, bh0 + WID,     Sw, lane, g, wof, rof, Bb, Ba);
    layer_body(WF8 + (size_t)(s * NHID + 2) * 2048, bh0 + 2 * WID, Sw, lane, g, wof, rof, Ba, Bb);

    // ---- output layer: row-0 A-frag MFMAs; raw[pt] = D row0 (g==0 lanes, reg0) ----
    {
        const f16x8* WOp = (const f16x8*)WoutF + s * 256;
        float bo = bout[s];
        f32x4 oc[4];
        #pragma unroll
        for (int pg = 0; pg < 4; ++pg) oc[pg] = (f32x4){bo, bo, bo, bo};
        #pragma unroll
        for (int kk = 0; kk < 4; ++kk) {
            f16x8 a = WOp[kk * 64 + lane];
            #pragma unroll
            for (int pg = 0; pg < 4; ++pg)
                oc[pg] = __builtin_amdgcn_mfma_f32_16x16x32_f16(a, Bb[pg][kk], oc[pg], 0, 0, 0);
        }
        if (g == 0) {
            #pragma unroll
            for (int pg = 0; pg < 4; ++pg)
                if (wmv[pg] > 0.f) atomicAdd(&out[n[pg]], wmv[pg] * oc[pg][0]);
        }
    }
}

extern "C" void kernel_launch(void* const* d_in, const int* in_sizes, int n_in,
                              void* d_out, int out_size, void* d_ws, size_t ws_size,
                              hipStream_t stream) {
    const float* x       = (const float*)d_in[0];
    const float* W0      = (const float*)d_in[1];
    const float* b0      = (const float*)d_in[2];
    const float* Wh      = (const float*)d_in[3];
    const float* bh      = (const float*)d_in[4];
    const float* Wout    = (const float*)d_in[5];
    const float* bout    = (const float*)d_in[6];
    const float* centres = (const float*)d_in[7];
    const float* scales  = (const float*)d_in[8];
    const float* mu_min  = (const float*)d_in[9];
    const float* sd_min  = (const float*)d_in[10];
    const float* mu_max  = (const float*)d_in[11];
    const float* sd_max  = (const float*)d_in[12];
    float* out = (float*)d_out;
    char* ws = (char*)d_ws;
    int*      counts = (int*)ws;
    int*      idx    = (int*)(ws + OFF_IDX);
    _Float16* WF     = (_Float16*)(ws + OFF_WF);
    _Float16* WoutF  = (_Float16*)(ws + OFF_WO);

    hipMemsetAsync(counts, 0, NS * CSTR * sizeof(int), stream);
    prep_kernel<<<dim3(656), dim3(256), 0, stream>>>(x, mu_min, sd_min, mu_max, sd_max,
                                                     counts, idx, out, Wh, WF, Wout, WoutF);
    dim3 grid(CAP / 256, NS);                     // x = tile (same-s blocks adjacent)
    mlp_kernel<<<grid, dim3(256), 0, stream>>>(x, W0, b0, WF, bh, WoutF, bout,
                                               centres, scales, mu_min, sd_min, mu_max, sd_max,
                                               counts, idx, out);
}